// Round 2
// baseline (173.866 us; speedup 1.0000x reference)
//
#include <hip/hip_runtime.h>
#include <hip/hip_bf16.h>
#include <stdint.h>

// DeformableBlock: fused [offset-conv (MFMA) + meta + deformable conv (MFMA GEMM)]
// -> GroupNorm+ReLU.  B=4, CIN=COUT=256, H=W=64, 3x3, GN groups=32.
// Round 11: L2-traffic attack (R10 showed occupancy-insensitive -> L2-BW theory).
//  - N=64 px/block (one image row), 256 blocks: A-panel (warr) traffic halved
//    (each A-frag feeds 4 N-subtiles). Gather threads own 2 pixels each.
//  - XCD-aware bijective swizzle: 32 consecutive rows of one image per XCD
//    -> per-XCD working set ~2.3 MB < 4 MB L2 (kills the FETCH_SIZE thrash).
//  - k_transpose + k_prep merged (4 -> 3 launches).

typedef unsigned short u16;
typedef __bf16 bf16x8 __attribute__((ext_vector_type(8)));
typedef float f32x4_t __attribute__((ext_vector_type(4)));

#define HW 4096

__device__ __forceinline__ uint32_t f32_to_bf16_rne(float f) {
  uint32_t u = __builtin_bit_cast(uint32_t, f);
  return (u + 0x7FFFu + ((u >> 16) & 1u)) >> 16;
}
__device__ __forceinline__ float bf_lo(uint32_t u) {
  return __builtin_bit_cast(float, u << 16);
}
__device__ __forceinline__ float bf_hi(uint32_t u) {
  return __builtin_bit_cast(float, u & 0xFFFF0000u);
}
__device__ __forceinline__ uint32_t blend2(uint32_t a, uint32_t b, uint32_t c,
                                           uint32_t d, float4 mw) {
  float lo = mw.x * bf_lo(a) + mw.y * bf_lo(b) + mw.z * bf_lo(c) + mw.w * bf_lo(d);
  float hi = mw.x * bf_hi(a) + mw.y * bf_hi(b) + mw.z * bf_hi(c) + mw.w * bf_hi(d);
  return f32_to_bf16_rne(lo) | (f32_to_bf16_rne(hi) << 16);
}

// ---------------- Kernel PRE: transpose + weight prep + zero part (merged) ----------------
// bid <  4096 : x NCHW f32 -> NHWC bf16
// bid <  6400 : warr[kc 36][g 8][m 256][kk 8]
// bid <  6688 : owm [kc 36][g 8][m 32][kk 8]
// bid == 6688 : zero part
__global__ __launch_bounds__(256) void k_pre(const float* __restrict__ x,
                                             const float* __restrict__ wsrc,
                                             const float* __restrict__ ow,
                                             u16* __restrict__ xt,
                                             u16* __restrict__ warr,
                                             u16* __restrict__ owm,
                                             float* __restrict__ part) {
  __shared__ float tile[32][33];
  int bid = blockIdx.x;
  int tid = threadIdx.x;
  if (bid < 4096) {
    int bx = bid & 127, by = (bid >> 7) & 7, bz = bid >> 10;
    int c0 = by * 32, p0 = bx * 32;
    int tx = tid & 31, ty = tid >> 5;  // 32 x 8
#pragma unroll
    for (int j = 0; j < 32; j += 8)
      tile[ty + j][tx] = x[(bz * 256 + c0 + ty + j) * HW + p0 + tx];
    __syncthreads();
    int cp = tid & 15;
    int pr = tid >> 4;
#pragma unroll
    for (int j = 0; j < 2; j++) {
      int p = pr + j * 16;
      uint32_t lo = f32_to_bf16_rne(tile[cp * 2][p]);
      uint32_t hi = f32_to_bf16_rne(tile[cp * 2 + 1][p]);
      *(uint32_t*)&xt[(bz * HW + p0 + p) * 256 + c0 + cp * 2] = lo | (hi << 16);
    }
  } else if (bid < 6400) {
    int e = (bid - 4096) * 256 + tid;  // < 589824
    int kk = e & 7, m = (e >> 3) & 255, g = (e >> 11) & 7, kc = e >> 14;
    int cin = (kc & 3) * 64 + g * 8 + kk;
    int tap = kc >> 2;
    warr[e] = (u16)f32_to_bf16_rne(wsrc[m * 2304 + cin * 9 + tap]);
  } else if (bid < 6688) {
    int e = (bid - 6400) * 256 + tid;  // < 73728
    int kk = e & 7, m = (e >> 3) & 31, g = (e >> 8) & 7, kc = e >> 11;
    int cin = (kc & 3) * 64 + g * 8 + kk;
    int tap = kc >> 2;
    float v = (m < 18) ? ow[m * 2304 + cin * 9 + tap] : 0.f;
    owm[e] = (u16)f32_to_bf16_rne(v);
  } else {
    part[tid] = 0.f;  // 4 b * 32 groups * {s,ss} = 256 floats
  }
}

// ---------------- Kernel C: FUSED offset-conv + meta + deformable GEMM + GN partials ----------------
// Block = (b, image row), 256 blocks x 512 threads (8 waves, M=32/wave, N=64 = 4 subtiles).
// Phase A: offset conv M=32, N=64 (two 32-px halves; waves 0-3 half 0, 4-7 half 1;
//          each wave does 9 kc-chunks, wave-private LDS staging, zero barriers).
// Meta -> LDS (576 = 9 taps x 64 px).
// Phase B: deformable GEMM M=256, N=64: 4 subtiles share each A-frag (halves warr L2
//          traffic vs N=32). K-chunk = 128 ch, B LDS double-buffered, gathers
//          prefetched one chunk ahead. Fused GN partial sums at the end.
__global__ __launch_bounds__(512) void k_conv(
    const u16* __restrict__ xt, const u16* __restrict__ warr,
    const u16* __restrict__ owm, const float* __restrict__ ob,
    float* __restrict__ out, float* __restrict__ part) {
  __shared__ char smem[54272];
  u16* stage = (u16*)smem;                   // phase A: [w8][2112 u16]  (33792 B)
  float* off_part = (float*)(smem + 33792);  // phase A: [w8][px32][20]  (20480 B)
  int4* ci_s = (int4*)smem;                  // meta/B:  [576]           (9216 B)
  float4* mw_s = (float4*)(smem + 9216);     // meta/B:  [576]           (9216 B)
  u16* b_s = (u16*)(smem + 18432);           // phase B: [2buf][4sub][16oct][136 u16] (34816 B)

  int tid = threadIdx.x;
  int lane = tid & 63;
  int wm = tid >> 6;  // 0..7
  // XCD-aware bijective swizzle (256 blocks, 8 XCDs): XCD x gets 32 consecutive
  // work-ids = 32 consecutive rows of ONE image -> L2 working set ~2.3 MB.
  int wk = (blockIdx.x & 7) * 32 + (blockIdx.x >> 3);
  int b = wk >> 6;
  int pt = wk & 63;   // image row
  int p0 = pt * 64;

  // ---- Phase A: offset conv; waves 0-3 -> px 0-31, waves 4-7 -> px 32-63 ----
  {
    u16* st = stage + wm * 2112;
    int half = wm >> 2, ww = wm & 3;
    int xh = half * 32;
    int q = lane & 15, pq = lane >> 4;
    int oct = lane & 7, pxs = lane >> 3;  // staging map (uint4 loads)
    f32x4_t a2[2][2] = {};
#pragma unroll 1
    for (int kc = ww; kc < 36; kc += 4) {
      int tap = kc >> 2, cc = kc & 3;
      int ky = tap / 3, kx = tap % 3;
      int yy = pt + ky - 1;
      bool vy = (yy >= 0) && (yy < 64);
#pragma unroll
      for (int i = 0; i < 4; i++) {
        int px = i * 8 + pxs;
        int xx2 = xh + px + kx - 1;
        uint4 v = make_uint4(0u, 0u, 0u, 0u);
        if (vy && xx2 >= 0 && xx2 < 64)
          v = *(const uint4*)&xt[(b * HW + yy * 64 + xx2) * 256 + cc * 64 + oct * 8];
        *(uint4*)&st[oct * 264 + px * 8] = v;
      }
#pragma unroll
      for (int ks = 0; ks < 2; ks++) {
        int g = ks * 4 + pq;
        const u16* ab = owm + kc * 2048 + g * 256;
#pragma unroll
        for (int s = 0; s < 2; s++) {
          bf16x8 bfr = *(bf16x8*)&st[g * 264 + (s * 16 + q) * 8];
#pragma unroll
          for (int im = 0; im < 2; im++) {
            bf16x8 af = *(const bf16x8*)&ab[(im * 16 + q) * 8];
            a2[s][im] = __builtin_amdgcn_mfma_f32_16x16x32_bf16(af, bfr, a2[s][im], 0, 0, 0);
          }
        }
      }
    }
    // D: col = q (px within 16-sub), row = pq*4+r (+im*16) = oc
#pragma unroll
    for (int s = 0; s < 2; s++)
#pragma unroll
      for (int im = 0; im < 2; im++)
#pragma unroll
        for (int r = 0; r < 4; r++) {
          int oc = im * 16 + pq * 4 + r;
          if (oc < 18) off_part[(wm * 32 + s * 16 + q) * 20 + oc] = a2[s][im][r];
        }
  }
  __syncthreads();
  // ---- meta: 576 = 9 taps x 64 px; results to LDS (aliases dead stage) ----
  for (int it = tid; it < 576; it += 512) {
    int tap = it >> 6;
    int px = it & 63;
    int half = px >> 5, px32 = px & 31;
    float dy = ob[2 * tap], dx = ob[2 * tap + 1];
#pragma unroll
    for (int wv = 0; wv < 4; wv++) {
      dy += off_part[((half * 4 + wv) * 32 + px32) * 20 + 2 * tap];
      dx += off_part[((half * 4 + wv) * 32 + px32) * 20 + 2 * tap + 1];
    }
    int ky = tap / 3, kx = tap % 3;
    float py = (float)(pt - 1 + ky) + dy;
    float pxx = (float)(px - 1 + kx) + dx;
    float y0f = floorf(py), x0f = floorf(pxx);
    float ty = py - y0f, tx = pxx - x0f;
    int y0 = (int)y0f, x0 = (int)x0f;
    int y1 = y0 + 1, x1 = x0 + 1;
    float wy0 = 1.f - ty, wy1 = ty, wx0 = 1.f - tx, wx1 = tx;
    bool vy0 = (y0 >= 0) && (y0 < 64), vy1 = (y1 >= 0) && (y1 < 64);
    bool vx0 = (x0 >= 0) && (x0 < 64), vx1 = (x1 >= 0) && (x1 < 64);
    int cy0 = min(max(y0, 0), 63), cy1 = min(max(y1, 0), 63);
    int cx0 = min(max(x0, 0), 63), cx1 = min(max(x1, 0), 63);
    int base = b * HW;
    int4 ci;
    ci.x = (base + cy0 * 64 + cx0) * 256;
    ci.y = (base + cy0 * 64 + cx1) * 256;
    ci.z = (base + cy1 * 64 + cx0) * 256;
    ci.w = (base + cy1 * 64 + cx1) * 256;
    float4 mw;
    mw.x = wy0 * wx0 * ((vy0 && vx0) ? 1.f : 0.f);
    mw.y = wy0 * wx1 * ((vy0 && vx1) ? 1.f : 0.f);
    mw.z = wy1 * wx0 * ((vy1 && vx0) ? 1.f : 0.f);
    mw.w = wy1 * wx1 * ((vy1 && vx1) ? 1.f : 0.f);
    ci_s[it] = ci;
    mw_s[it] = mw;
  }
  __syncthreads();

  // ---- Phase B: deformable GEMM M=256, N=64 (4 subtiles share A frags) ----
  {
    int oct8 = tid & 15;   // channel octet within 128-ch chunk
    int pxg = tid >> 4;    // 0..31: this thread gathers px pxg and pxg+32
    int suba = pxg >> 4;   // subtile of first px (0/1); second is suba+2
    int pxw = pxg & 15;
    int col = lane & 15;
    int pq = lane >> 4;
    f32x4_t acc[4][2] = {};  // [sub][im]

    // prologue: gather dccg=0 (tap 0)
    int e0 = oct8 * 8;
    int4 cia = ci_s[pxg];
    float4 mwa = mw_s[pxg];
    int4 cib = ci_s[32 + pxg];
    float4 mwb = mw_s[32 + pxg];
    uint4 g0 = *(const uint4*)&xt[cia.x + e0];
    uint4 g1 = *(const uint4*)&xt[cia.y + e0];
    uint4 g2 = *(const uint4*)&xt[cia.z + e0];
    uint4 g3 = *(const uint4*)&xt[cia.w + e0];
    uint4 h0 = *(const uint4*)&xt[cib.x + e0];
    uint4 h1 = *(const uint4*)&xt[cib.y + e0];
    uint4 h2 = *(const uint4*)&xt[cib.z + e0];
    uint4 h3 = *(const uint4*)&xt[cib.w + e0];

#pragma unroll 1
    for (int dccg = 0; dccg < 18; dccg++) {
      u16* bb = b_s + (dccg & 1) * 8704;
      // blend current chunk -> LDS (two pixels per thread)
      {
        uint4 u;
        u.x = blend2(g0.x, g1.x, g2.x, g3.x, mwa);
        u.y = blend2(g0.y, g1.y, g2.y, g3.y, mwa);
        u.z = blend2(g0.z, g1.z, g2.z, g3.z, mwa);
        u.w = blend2(g0.w, g1.w, g2.w, g3.w, mwa);
        *(uint4*)&bb[suba * 2176 + oct8 * 136 + pxw * 8] = u;
      }
      {
        uint4 u;
        u.x = blend2(h0.x, h1.x, h2.x, h3.x, mwb);
        u.y = blend2(h0.y, h1.y, h2.y, h3.y, mwb);
        u.z = blend2(h0.z, h1.z, h2.z, h3.z, mwb);
        u.w = blend2(h0.w, h1.w, h2.w, h3.w, mwb);
        *(uint4*)&bb[(suba + 2) * 2176 + oct8 * 136 + pxw * 8] = u;
      }
      __syncthreads();
      // prefetch next chunk's gathers (hidden under MFMA + next barrier)
      if (dccg < 17) {
        int nx = dccg + 1;
        int tapn = nx >> 1;
        int en = (nx & 1) * 128 + e0;
        cia = ci_s[tapn * 64 + pxg];
        mwa = mw_s[tapn * 64 + pxg];
        cib = ci_s[tapn * 64 + 32 + pxg];
        mwb = mw_s[tapn * 64 + 32 + pxg];
        g0 = *(const uint4*)&xt[cia.x + en];
        g1 = *(const uint4*)&xt[cia.y + en];
        g2 = *(const uint4*)&xt[cia.z + en];
        g3 = *(const uint4*)&xt[cia.w + en];
        h0 = *(const uint4*)&xt[cib.x + en];
        h1 = *(const uint4*)&xt[cib.y + en];
        h2 = *(const uint4*)&xt[cib.z + en];
        h3 = *(const uint4*)&xt[cib.w + en];
      }
      // MFMA on current chunk (K=128 -> 4 K-steps, 4 subtiles share A frags)
      int tap = dccg >> 1, dcc = dccg & 1;
#pragma unroll
      for (int ks = 0; ks < 4; ks++) {
        int ro = ks * 4 + pq;
        bf16x8 b0 = *(bf16x8*)&bb[ro * 136 + col * 8];
        bf16x8 b1 = *(bf16x8*)&bb[2176 + ro * 136 + col * 8];
        bf16x8 b2 = *(bf16x8*)&bb[4352 + ro * 136 + col * 8];
        bf16x8 b3 = *(bf16x8*)&bb[6528 + ro * 136 + col * 8];
        int kc = tap * 4 + dcc * 2 + (ks >> 1);
        int gg = (ks & 1) * 4 + pq;
        const u16* ab = warr + kc * 16384 + gg * 2048 + (wm * 32 + col) * 8;
#pragma unroll
        for (int im = 0; im < 2; im++) {
          bf16x8 af = *(const bf16x8*)&ab[im * 128];
          acc[0][im] = __builtin_amdgcn_mfma_f32_16x16x32_bf16(af, b0, acc[0][im], 0, 0, 0);
          acc[1][im] = __builtin_amdgcn_mfma_f32_16x16x32_bf16(af, b1, acc[1][im], 0, 0, 0);
          acc[2][im] = __builtin_amdgcn_mfma_f32_16x16x32_bf16(af, b2, acc[2][im], 0, 0, 0);
          acc[3][im] = __builtin_amdgcn_mfma_f32_16x16x32_bf16(af, b3, acc[3][im], 0, 0, 0);
        }
      }
      // no trailing barrier: next dccg writes the other buffer (2-deep rotation safe)
    }

    // epilogue: D col=px-in-sub, row=pq*4+r -> NCHW; fused GN partial sums
#pragma unroll
    for (int im = 0; im < 2; im++) {
      float s = 0.f, ss = 0.f;
#pragma unroll
      for (int sb = 0; sb < 4; sb++) {
        int n = p0 + sb * 16 + col;
#pragma unroll
        for (int r = 0; r < 4; r++) {
          int m = wm * 32 + im * 16 + pq * 4 + r;
          float v = acc[sb][im][r];
          out[(b * 256 + m) * HW + n] = v;
          s += v;
          ss += v * v;
        }
      }
      // this thread's 16 values all share one GN group; reduce over 32-lane halves
#pragma unroll
      for (int msk = 1; msk <= 16; msk <<= 1) {
        s += __shfl_xor(s, msk);
        ss += __shfl_xor(ss, msk);
      }
      if ((lane & 31) == 0) {
        int grp = wm * 4 + im * 2 + (lane >> 5);
        float* pp = part + (b * 32 + grp) * 2;
        atomicAdd(pp, s);
        atomicAdd(pp + 1, ss);
      }
    }
  }
}

// ---------------- Kernel N: finalize stats + normalize + ReLU in place ----------------
__global__ __launch_bounds__(256) void k_gn_apply(float* __restrict__ out,
                                                  const float2* __restrict__ part,
                                                  const float* __restrict__ gamma,
                                                  const float* __restrict__ beta) {
  __shared__ float sga, sbe;
  int gid = blockIdx.x * 256 + threadIdx.x;  // float4 index, < 1048576
  int c = (gid >> 10) & 255;
  int bb = gid >> 18;
  if (threadIdx.x == 0) {
    float2 p = part[bb * 32 + (c >> 3)];
    float mu = p.x / 32768.f;
    float var = p.y / 32768.f - mu * mu;
    float rs = rsqrtf(var + 1e-5f);
    float ga = gamma[c] * rs;
    sga = ga;
    sbe = beta[c] - mu * ga;
  }
  __syncthreads();
  float ga = sga, be = sbe;
  float4 v = ((const float4*)out)[gid];
  v.x = fmaxf(v.x * ga + be, 0.f);
  v.y = fmaxf(v.y * ga + be, 0.f);
  v.z = fmaxf(v.z * ga + be, 0.f);
  v.w = fmaxf(v.w * ga + be, 0.f);
  ((float4*)out)[gid] = v;
}

extern "C" void kernel_launch(void* const* d_in, const int* in_sizes, int n_in,
                              void* d_out, int out_size, void* d_ws, size_t ws_size,
                              hipStream_t stream) {
  const float* x = (const float*)d_in[0];
  const float* offset_w = (const float*)d_in[1];
  const float* offset_b = (const float*)d_in[2];
  const float* deform_w = (const float*)d_in[3];
  const float* gn_gamma = (const float*)d_in[4];
  const float* gn_beta = (const float*)d_in[5];
  float* out = (float*)d_out;
  char* ws = (char*)d_ws;

  u16* xt = (u16*)ws;                      //  8,388,608 B (bf16 NHWC)
  u16* warr = (u16*)(ws + 8388608);        //  1,179,648 B
  u16* owm = (u16*)(ws + 9568256);         //    147,456 B
  float* part = (float*)(ws + 9715712);    //      1,024 B (4b x 32g x {s,ss})

  k_pre<<<dim3(6689), dim3(256), 0, stream>>>(x, deform_w, offset_w, xt, warr, owm, part);
  k_conv<<<dim3(256), dim3(512), 0, stream>>>(xt, warr, owm, offset_b, out, part);
  k_gn_apply<<<dim3(4096), dim3(256), 0, stream>>>(out, (const float2*)part, gn_gamma, gn_beta);
}